// Round 5
// baseline (1046.300 us; speedup 1.0000x reference)
//
#include <hip/hip_runtime.h>
#include <hip/hip_bf16.h>
#include <type_traits>

typedef _Float16 half8_t __attribute__((ext_vector_type(8)));
typedef _Float16 half4_t __attribute__((ext_vector_type(4)));
typedef _Float16 half2_t __attribute__((ext_vector_type(2)));
typedef float f32x4 __attribute__((ext_vector_type(4)));

// ---------------- CSR build ----------------
// harness delivers integer inputs as int32 (edge_index int64 -> const int*).

static __global__ __launch_bounds__(256) void k_zero(int* __restrict__ a, int n) {
  int i = blockIdx.x * 256 + threadIdx.x;
  if (i < n) a[i] = 0;
}

static __global__ __launch_bounds__(256) void k_deg(const int* __restrict__ ei,
                                                    int* __restrict__ deg, int E) {
  int e = blockIdx.x * 256 + threadIdx.x;
  if (e < E) atomicAdd(&deg[ei[E + e]], 1);  // dst = ei[1][e]
}

static __global__ __launch_bounds__(256) void k_chunk_sum(const int* __restrict__ deg,
                                                          int* __restrict__ bsum, int n) {
  int t = threadIdx.x;
  int base = blockIdx.x * 1024 + t * 4;
  int s = 0;
#pragma unroll
  for (int j = 0; j < 4; j++) {
    int idx = base + j;
    if (idx < n) s += deg[idx];
  }
  __shared__ int red[256];
  red[t] = s;
  __syncthreads();
  for (int off = 128; off > 0; off >>= 1) {
    if (t < off) red[t] += red[t + off];
    __syncthreads();
  }
  if (t == 0) bsum[blockIdx.x] = red[0];
}

static __global__ void k_scan_bsum(int* bsum, int nb) {
  if (threadIdx.x == 0 && blockIdx.x == 0) {
    int run = 0;
    for (int i = 0; i < nb; i++) {
      int v = bsum[i];
      bsum[i] = run;
      run += v;
    }
  }
}

static __global__ __launch_bounds__(256) void k_scan_final(const int* __restrict__ deg,
                                                           const int* __restrict__ bsum,
                                                           int* __restrict__ rs,
                                                           float* __restrict__ dinv,
                                                           int n, int Etot) {
  int t = threadIdx.x;
  int base = blockIdx.x * 1024 + t * 4;
  int v[4];
  int s = 0;
#pragma unroll
  for (int j = 0; j < 4; j++) {
    int idx = base + j;
    v[j] = (idx < n) ? deg[idx] : 0;
    s += v[j];
  }
  __shared__ int sc[256];
  sc[t] = s;
  __syncthreads();
  for (int off = 1; off < 256; off <<= 1) {
    int add = (t >= off) ? sc[t - off] : 0;
    __syncthreads();
    sc[t] += add;
    __syncthreads();
  }
  int run = sc[t] - s + bsum[blockIdx.x];
#pragma unroll
  for (int j = 0; j < 4; j++) {
    int idx = base + j;
    if (idx < n) {
      rs[idx] = run;
      dinv[idx] = v[j] > 0 ? 1.0f / (float)v[j] : 0.0f;
      run += v[j];
    }
  }
  if (blockIdx.x == 0 && t == 0) rs[n] = Etot;
}

static __global__ __launch_bounds__(256) void k_fill(const int* __restrict__ ei,
                                                     const int* __restrict__ rs,
                                                     int* __restrict__ cursor,
                                                     int* __restrict__ srcs, int E) {
  int e = blockIdx.x * 256 + threadIdx.x;
  if (e < E) {
    int d = ei[E + e];
    int s = ei[e];
    int pos = atomicAdd(&cursor[d], 1);
    srcs[rs[d] + pos] = s;
  }
}

// ---------------- casts ----------------

static __global__ __launch_bounds__(256) void k_cast_f16(const float* __restrict__ in,
                                                         _Float16* __restrict__ out, int n4) {
  int i = blockIdx.x * 256 + threadIdx.x;
  if (i < n4) {
    float4 v = reinterpret_cast<const float4*>(in)[i];
    half4_t h;
    h[0] = (_Float16)v.x;
    h[1] = (_Float16)v.y;
    h[2] = (_Float16)v.z;
    h[3] = (_Float16)v.w;
    reinterpret_cast<half4_t*>(out)[i] = h;
  }
}

// ---------------- fused layer: mean-agg (LDS) + dual GEMM + bias + relu ----------------
// Block: 256 threads = 4 waves, owns 64 dst rows.
// Phase 1: wave w mean-aggregates rows i0+w*16..+15 into XOR-swizzled LDS tile.
// Phase 2: out[i][o] = relu(b[o] + sum_k mean[i][k]Wl[o][k] + sum_k x[i][k]Wr[o][k])
//   A(mean) from LDS, A(x) from global, B from global (L2-resident weights).

template <int DIN, bool LAST>
static __global__ __launch_bounds__(256) void k_fused(const _Float16* __restrict__ x,
                                                      const int* __restrict__ srcs,
                                                      const int* __restrict__ rs,
                                                      const float* __restrict__ dinv,
                                                      const _Float16* __restrict__ wl,
                                                      const _Float16* __restrict__ wr,
                                                      const float* __restrict__ bias,
                                                      _Float16* __restrict__ yout,
                                                      float* __restrict__ fout, int n) {
  constexpr int EPL = DIN / 64;  // f16 elems per lane per row
  using hv = typename std::conditional<EPL == 2, half2_t, half4_t>::type;
  __shared__ _Float16 meanT[64 * DIN];
  int lane = threadIdx.x & 63;
  int w = threadIdx.x >> 6;
  int i0 = blockIdx.x * 64;

  // ---- phase 1: mean aggregation ----
  for (int q = 0; q < 16; ++q) {
    int li = w * 16 + q;
    int i = i0 + li;
    float acc[EPL];
#pragma unroll
    for (int j = 0; j < EPL; j++) acc[j] = 0.0f;
    if (i < n) {
      int e0 = rs[i], e1 = rs[i + 1];
      int co = lane * EPL;
      int e = e0;
      for (; e + 4 <= e1; e += 4) {
        int s0 = srcs[e + 0], s1 = srcs[e + 1], s2 = srcs[e + 2], s3 = srcs[e + 3];
        hv v0 = *(const hv*)(x + (size_t)s0 * DIN + co);
        hv v1 = *(const hv*)(x + (size_t)s1 * DIN + co);
        hv v2 = *(const hv*)(x + (size_t)s2 * DIN + co);
        hv v3 = *(const hv*)(x + (size_t)s3 * DIN + co);
#pragma unroll
        for (int j = 0; j < EPL; j++)
          acc[j] += (float)v0[j] + (float)v1[j] + (float)v2[j] + (float)v3[j];
      }
      for (; e < e1; ++e) {
        int s = srcs[e];
        hv v = *(const hv*)(x + (size_t)s * DIN + co);
#pragma unroll
        for (int j = 0; j < EPL; j++) acc[j] += (float)v[j];
      }
      float di = dinv[i];
#pragma unroll
      for (int j = 0; j < EPL; j++) acc[j] *= di;
    }
    // swizzled LDS write (element-index XOR of bits 3..6; accesses stay in 8-elem units)
    unsigned idx = (unsigned)li * DIN + lane * EPL;
    idx ^= ((li & 15) << 3);
    hv o;
#pragma unroll
    for (int j = 0; j < EPL; j++) o[j] = (_Float16)acc[j];
    *(hv*)&meanT[idx] = o;
  }
  __syncthreads();

  // ---- phase 2: dual GEMM ----
  int lr = lane & 15;
  int kq = lane >> 4;
  int n0 = w * 64;
  f32x4 acc2[4][4];
#pragma unroll
  for (int m = 0; m < 4; m++)
#pragma unroll
    for (int nn = 0; nn < 4; nn++) acc2[m][nn] = (f32x4)0.0f;

#pragma unroll 2
  for (int ks = 0; ks < DIN / 16; ++ks) {  // 2*DIN/32 k-steps
    int k0 = ks * 32;
    half8_t a[4], b[4];
    if (k0 < DIN) {
      // A = mean tile from LDS (swizzled)
#pragma unroll
      for (int m = 0; m < 4; m++) {
        int r = m * 16 + lr;
        unsigned idx = (unsigned)r * DIN + k0 + kq * 8;
        idx ^= ((r & 15) << 3);
        a[m] = *(const half8_t*)&meanT[idx];
      }
#pragma unroll
      for (int nn = 0; nn < 4; nn++) {
        int col = n0 + nn * 16 + lr;
        b[nn] = *(const half8_t*)(wl + (size_t)col * DIN + k0 + kq * 8);
      }
    } else {
      int kk = k0 - DIN;
#pragma unroll
      for (int m = 0; m < 4; m++) {
        int row = i0 + m * 16 + lr;
        if (row >= n) row = n - 1;  // clamp; stores guarded
        a[m] = *(const half8_t*)(x + (size_t)row * DIN + kk + kq * 8);
      }
#pragma unroll
      for (int nn = 0; nn < 4; nn++) {
        int col = n0 + nn * 16 + lr;
        b[nn] = *(const half8_t*)(wr + (size_t)col * DIN + kk + kq * 8);
      }
    }
#pragma unroll
    for (int m = 0; m < 4; m++)
#pragma unroll
      for (int nn = 0; nn < 4; nn++)
        acc2[m][nn] = __builtin_amdgcn_mfma_f32_16x16x32_f16(a[m], b[nn], acc2[m][nn], 0, 0, 0);
  }

  // ---- epilogue ----
#pragma unroll
  for (int nn = 0; nn < 4; nn++) {
    int col = n0 + nn * 16 + lr;  // D col = lane&15
    float bv = bias[col];
#pragma unroll
    for (int m = 0; m < 4; m++) {
#pragma unroll
      for (int r = 0; r < 4; r++) {
        int row = i0 + m * 16 + kq * 4 + r;  // D row = (lane>>4)*4 + r
        if (row < n) {
          float v = acc2[m][nn][r] + bv;
          v = v > 0.0f ? v : 0.0f;
          if constexpr (LAST)
            fout[(size_t)row * 256 + col] = v;
          else
            yout[(size_t)row * 256 + col] = (_Float16)v;
        }
      }
    }
  }
}

// ---------------- host launch ----------------
// Memory map (audited for per-call read-before-write and no cross-call state):
//   ws  : xbuf(51.2M) srcs(6.4M) rs deg cursor dinv bsum weights(f16)  ~= 61 MB
//   dout: [0,51.2M) y0 f16 (L0 out); [51.2M,76.8M) x0 f16 (feature cast)
//         L2 writes full d_out f32 last; x0/y0 dead by then; all rebuilt next call.

extern "C" void kernel_launch(void* const* d_in, const int* in_sizes, int n_in,
                              void* d_out, int out_size, void* d_ws, size_t ws_size,
                              hipStream_t stream) {
  const float* feat = (const float*)d_in[0];
  const int* ei = (const int*)d_in[1];
  const float* Wl[3] = {(const float*)d_in[2], (const float*)d_in[5], (const float*)d_in[8]};
  const float* Wr[3] = {(const float*)d_in[3], (const float*)d_in[6], (const float*)d_in[9]};
  const float* Bv[3] = {(const float*)d_in[4], (const float*)d_in[7], (const float*)d_in[10]};
  int N = in_sizes[0] / 128;
  int E = in_sizes[1] / 2;

  char* p = (char*)d_ws;
  auto carve = [&](size_t bytes) {
    char* r = p;
    p += (bytes + 255) & ~(size_t)255;
    return r;
  };
  _Float16* xbuf = (_Float16*)carve((size_t)N * 256 * 2);  // layer-1 output
  int* srcs = (int*)carve((size_t)E * 4);
  int* rs = (int*)carve((size_t)(N + 1) * 4);
  int* deg = (int*)carve((size_t)N * 4);
  int* cursor = (int*)carve((size_t)N * 4);
  float* dinv = (float*)carve((size_t)N * 4);
  int* bsum = (int*)carve(4096);
  const int din[3] = {128, 256, 256};
  _Float16* wlh[3];
  _Float16* wrh[3];
  for (int l = 0; l < 3; l++) {
    wlh[l] = (_Float16*)carve((size_t)256 * din[l] * 2);
    wrh[l] = (_Float16*)carve((size_t)256 * din[l] * 2);
  }

  _Float16* y0 = (_Float16*)d_out;                            // [N][256] f16
  _Float16* x0 = (_Float16*)((char*)d_out + (size_t)N * 512); // [N][128] f16 in upper half

  // CSR build (kernel-zeroed, no memset nodes)
  int nzb = (2 * N + 255) / 256;
  k_zero<<<nzb, 256, 0, stream>>>(deg, N);       // deg and cursor are adjacent carves,
  k_zero<<<nzb, 256, 0, stream>>>(cursor, N);    // zero each explicitly
  k_deg<<<(E + 255) / 256, 256, 0, stream>>>(ei, deg, E);
  int nb = (N + 1023) / 1024;
  k_chunk_sum<<<nb, 256, 0, stream>>>(deg, bsum, N);
  k_scan_bsum<<<1, 64, 0, stream>>>(bsum, nb);
  k_scan_final<<<nb, 256, 0, stream>>>(deg, bsum, rs, dinv, N, E);
  k_fill<<<(E + 255) / 256, 256, 0, stream>>>(ei, rs, cursor, srcs, E);

  // casts
  k_cast_f16<<<((N * 128 / 4) + 255) / 256, 256, 0, stream>>>(feat, x0, N * 128 / 4);
  for (int l = 0; l < 3; l++) {
    int n4 = 256 * din[l] / 4;
    k_cast_f16<<<(n4 + 255) / 256, 256, 0, stream>>>(Wl[l], wlh[l], n4);
    k_cast_f16<<<(n4 + 255) / 256, 256, 0, stream>>>(Wr[l], wrh[l], n4);
  }

  int grid = (N + 63) / 64;
  k_fused<128, false><<<grid, 256, 0, stream>>>(x0, srcs, rs, dinv, wlh[0], wrh[0], Bv[0], y0,
                                                nullptr, N);
  k_fused<256, false><<<grid, 256, 0, stream>>>(y0, srcs, rs, dinv, wlh[1], wrh[1], Bv[1], xbuf,
                                                nullptr, N);
  k_fused<256, true><<<grid, 256, 0, stream>>>(xbuf, srcs, rs, dinv, wlh[2], wrh[2], Bv[2], nullptr,
                                               (float*)d_out, N);
}